// Round 16
// baseline (187.590 us; speedup 1.0000x reference)
//
#include <hip/hip_runtime.h>
#include <hip/hip_bf16.h>

// DRSA temporal block. B=2, P=8, hp=8, W=24, C=256, NH=8, dk=32, kv=4, H=64.
// 5 dispatches: wtransA(+qkloc), compose(+topk), gemm_quad, attn_conv
// (interleaved; conv reverted to round-14 2-m-tile uniform-LDS form — the 3-m-tile
// "zero waste" variant regressed 3us: latency-bound, padding MFMAs were free),
// gemm_wo_ln2 (16-row tiles, 192 blocks).

#define NPOS 3072
#define CD   256
#define NE   (NPOS*CD)

typedef short bf16x8 __attribute__((ext_vector_type(8)));
typedef float f32x4  __attribute__((ext_vector_type(4)));

__device__ inline ushort f2bf(float f) {
    __hip_bfloat16 h = __float2bfloat16(f);   // RNE
    return *reinterpret_cast<ushort*>(&h);
}
__device__ inline float bf2f(ushort u) {
    unsigned v = ((unsigned)u) << 16;
    return *reinterpret_cast<float*>(&v);
}
__device__ inline bf16x8 addbf(bf16x8 a, bf16x8 b) {
    bf16x8 o;
    #pragma unroll
    for (int j = 0; j < 8; ++j)
        o[j] = (short)f2bf(bf2f((ushort)a[j]) + bf2f((ushort)b[j]));
    return o;
}

// ---------------------------------------------------------------- prep: transposes + copies + qkloc
__global__ __launch_bounds__(256) void wtransA(
    const float* __restrict__ w0, const float* __restrict__ w1, const float* __restrict__ w2,
    const float* __restrict__ w3, const float* __restrict__ w4, const float* __restrict__ w5,
    const float* __restrict__ w6, const float* __restrict__ cw,
    ushort* __restrict__ wt, ushort* __restrict__ wct, ushort* __restrict__ wstr,
    const float* __restrict__ x,
    const float* __restrict__ bq, const float* __restrict__ bk,
    float* __restrict__ qloc, float* __restrict__ kloc)
{
    __shared__ float l[64*65];
    int blk = blockIdx.x;
    int tid = threadIdx.x;
    if (blk < 512) {
        const float* M;
        ushort* D;
        int r2;
        if (blk < 112) {
            int mat = blk >> 4; r2 = blk & 15;
            M = mat==0?w0:mat==1?w1:mat==2?w2:mat==3?w3:mat==4?w4:mat==5?w5:w6;
            D = wt + (size_t)mat*65536;
        } else {
            int b2 = blk - 112;
            int tap = b2 >> 4; r2 = b2 & 15;
            M = cw + (size_t)tap*65536;
            D = wct + (size_t)tap*65536;
        }
        int ci0 = (r2 >> 2)*64, co0 = (r2 & 3)*64;
        int a = tid >> 6, c = tid & 63;
        #pragma unroll 4
        for (int k = 0; k < 16; ++k) {
            int cil = k*4 + a;
            l[cil*65 + c] = M[(size_t)(ci0 + cil)*256 + co0 + c];
        }
        __syncthreads();
        #pragma unroll 4
        for (int k = 0; k < 16; ++k) {
            int col = k*4 + a;
            D[((size_t)(co0 + col))*256 + ci0 + c] = f2bf(l[c*65 + col]);
        }
    } else if (blk < 524) {
        int b2 = blk - 512;
        int mat = b2 >> 2, quarter = b2 & 3;
        const float* M = mat==0 ? w0 : (mat==1 ? w1 : w2);
        size_t base = (size_t)quarter*16384;
        #pragma unroll
        for (int i = 0; i < 16; ++i) {
            size_t idx = base + (size_t)i*1024 + tid*4;
            float4 v = *(const float4*)(M + idx);
            ushort4 o;
            o.x = f2bf(v.x); o.y = f2bf(v.y); o.z = f2bf(v.z); o.w = f2bf(v.w);
            *(ushort4*)(wstr + (size_t)mat*65536 + idx) = o;
        }
    } else {
        int q2 = blk - 524;          // 0..31
        int bp = q2 & 15, which = q2 >> 4;
        int c = tid;
        float s = 0.f;
        for (int i = 0; i < 192; ++i)
            s += x[((size_t)(bp*192 + i))*256 + c];
        l[c] = s * (1.0f/192.0f);
        __syncthreads();
        const float* W  = which ? w1 : w0;   // wk : wq (fp32 exact)
        const float* Bv = which ? bk : bq;
        float* dst      = which ? kloc : qloc;
        float acc = Bv[c];
        #pragma unroll 8
        for (int k = 0; k < 256; ++k)
            acc += l[k] * W[(size_t)k*256 + c];
        dst[bp*256 + c] = acc;
    }
}

// ---------------------------------------------------------------- weight composition + topk
__global__ __launch_bounds__(256) void compose(
    const ushort* __restrict__ wt7, const ushort* __restrict__ wstr,
    const float* __restrict__ bq, const float* __restrict__ bk, const float* __restrict__ bv,
    const float* __restrict__ bqa, const float* __restrict__ bka, const float* __restrict__ bva,
    ushort* __restrict__ wtc, ushort* __restrict__ wtkv, float* __restrict__ bcomp,
    const float* __restrict__ qloc, const float* __restrict__ kloc, int* __restrict__ Rix)
{
    __shared__ __align__(16) ushort As[32*264];
    int y = blockIdx.y;
    int tid = threadIdx.x;
    if (y < 3) {
        const ushort* A = wt7 + (size_t)(3 + y)*65536;
        const ushort* T = wstr + (size_t)y*65536;
        ushort* U = wtc + (size_t)y*65536;
        int m0 = (blockIdx.x >> 1)*32;
        int nh = blockIdx.x & 1;
        #pragma unroll
        for (int i = 0; i < 4; ++i) {
            int c = i*256 + tid;
            int pos = c >> 5, off = (c & 31)*8;
            *(bf16x8*)&As[pos*264 + off] = *(const bf16x8*)(A + (size_t)(m0 + pos)*256 + off);
        }
        __syncthreads();
        int w = tid >> 6, lane = tid & 63, lm = lane & 15, lq = lane >> 4;
        const ushort* tb = T + ((size_t)(nh*128 + w*32 + lm))*256 + lq*8;
        f32x4 acc[2][2];
        #pragma unroll
        for (int mt = 0; mt < 2; ++mt)
            #pragma unroll
            for (int nt = 0; nt < 2; ++nt) acc[mt][nt] = (f32x4){0.f,0.f,0.f,0.f};
        for (int kc = 0; kc < 8; ++kc) {
            bf16x8 bw[2];
            #pragma unroll
            for (int nt = 0; nt < 2; ++nt) bw[nt] = *(const bf16x8*)(tb + nt*4096 + kc*32);
            bf16x8 af[2];
            #pragma unroll
            for (int mt = 0; mt < 2; ++mt)
                af[mt] = *(const bf16x8*)&As[(mt*16 + lm)*264 + kc*32 + lq*8];
            #pragma unroll
            for (int mt = 0; mt < 2; ++mt)
                #pragma unroll
                for (int nt = 0; nt < 2; ++nt)
                    acc[mt][nt] = __builtin_amdgcn_mfma_f32_16x16x32_bf16(af[mt], bw[nt], acc[mt][nt], 0,0,0);
        }
        #pragma unroll
        for (int mt = 0; mt < 2; ++mt)
            #pragma unroll
            for (int nt = 0; nt < 2; ++nt) {
                int n = nh*128 + w*32 + nt*16 + lm;
                #pragma unroll
                for (int j = 0; j < 4; ++j) {
                    int m = m0 + mt*16 + lq*4 + j;
                    U[(size_t)m*256 + n] = f2bf(acc[mt][nt][j]);
                }
            }
    } else if (y == 3) {
        const ushort* wk7 = wt7 + 65536;
        const ushort* wv7 = wt7 + 131072;
        size_t base = (size_t)blockIdx.x*4096 + tid*16;
        #pragma unroll
        for (int i = 0; i < 2; ++i) {
            bf16x8 a = *(const bf16x8*)(wk7 + base + i*8);
            bf16x8 b = *(const bf16x8*)(wv7 + base + i*8);
            *(bf16x8*)(wtkv + base + i*8) = addbf(a, b);
        }
        int bx = blockIdx.x;
        if (bx < 3) {
            const float* bsrc = bx==0 ? bq : (bx==1 ? bk : bv);
            const float* basr = bx==0 ? bqa : (bx==1 ? bka : bva);
            const ushort* wa = wt7 + (size_t)(3 + bx)*65536;
            float s = basr[tid];
            for (int k = 0; k < 256; ++k)
                s += bsrc[k] * bf2f(wa[(size_t)tid*256 + k]);
            bcomp[bx*256 + tid] = s;
        } else if (bx == 3) {
            bcomp[3*256 + tid] = bk[tid] + bv[tid];
        }
    } else {
        if (blockIdx.x >= 2) return;
        float* S = (float*)As;
        int b = blockIdx.x, t = tid;
        if (t < 64) {
            int p = t >> 3, qq = t & 7;
            float s = 0.f;
            for (int c = 0; c < 256; ++c)
                s += qloc[(b*8+p)*256 + c] * kloc[(b*8+qq)*256 + c];
            S[t] = s;
        }
        __syncthreads();
        if (t < 8) {
            float vals[8];
            #pragma unroll
            for (int j = 0; j < 8; ++j) vals[j] = S[t*8 + j];
            for (int j = 0; j < 4; ++j) {
                int best = 0; float bv2 = vals[0];
                #pragma unroll
                for (int i = 1; i < 8; ++i) if (vals[i] > bv2) { bv2 = vals[i]; best = i; }
                Rix[(b*8 + t)*4 + j] = best;
                vals[best] = -1e30f;
            }
        }
    }
}

// ---------------------------------------------------------------- quad GEMM from x (fp32 A)
__global__ __launch_bounds__(256) void gemm_quad(
    const float* __restrict__ A,
    const ushort* __restrict__ wtc, const ushort* __restrict__ wtkv,
    const float* __restrict__ bcomp,
    ushort* __restrict__ U0, ushort* __restrict__ U1,
    ushort* __restrict__ U2, ushort* __restrict__ U3)
{
    __shared__ __align__(16) ushort As[32*264];
    int y = blockIdx.y;
    const ushort* T = (y < 3) ? (wtc + (size_t)y*65536) : wtkv;
    const float* Bi = bcomp + y*256;
    ushort* U = y==0 ? U0 : (y==1 ? U1 : (y==2 ? U2 : U3));
    float sc = (y == 0) ? 0.17677669529663687f : 1.0f;
    int tid = threadIdx.x;
    int m0 = (blockIdx.x >> 1)*32;
    int nh = blockIdx.x & 1;
    #pragma unroll
    for (int i = 0; i < 4; ++i) {
        int c = i*256 + tid;
        int pos = c >> 5, off = (c & 31)*8;
        const float* src = A + (size_t)(m0 + pos)*256 + off;
        float4 v0 = *(const float4*)src;
        float4 v1 = *(const float4*)(src + 4);
        ushort4 o0, o1;
        o0.x = f2bf(v0.x); o0.y = f2bf(v0.y); o0.z = f2bf(v0.z); o0.w = f2bf(v0.w);
        o1.x = f2bf(v1.x); o1.y = f2bf(v1.y); o1.z = f2bf(v1.z); o1.w = f2bf(v1.w);
        *(ushort4*)&As[pos*264 + off]     = o0;
        *(ushort4*)&As[pos*264 + off + 4] = o1;
    }
    __syncthreads();
    int w = tid >> 6, lane = tid & 63, lm = lane & 15, lq = lane >> 4;
    const ushort* tb = T + ((size_t)(nh*128 + w*32 + lm))*256 + lq*8;

    f32x4 acc[2][2];
    #pragma unroll
    for (int mt = 0; mt < 2; ++mt)
        #pragma unroll
        for (int nt = 0; nt < 2; ++nt) acc[mt][nt] = (f32x4){0.f,0.f,0.f,0.f};

    bf16x8 bw[2];
    #pragma unroll
    for (int nt = 0; nt < 2; ++nt) bw[nt] = *(const bf16x8*)(tb + nt*4096);

    for (int kc = 0; kc < 8; ++kc) {
        int nk = (kc + 1 < 8) ? kc + 1 : 7;
        bf16x8 bn[2];
        #pragma unroll
        for (int nt = 0; nt < 2; ++nt) bn[nt] = *(const bf16x8*)(tb + nt*4096 + nk*32);
        bf16x8 af[2];
        #pragma unroll
        for (int mt = 0; mt < 2; ++mt)
            af[mt] = *(const bf16x8*)&As[(mt*16 + lm)*264 + kc*32 + lq*8];
        #pragma unroll
        for (int mt = 0; mt < 2; ++mt)
            #pragma unroll
            for (int nt = 0; nt < 2; ++nt)
                acc[mt][nt] = __builtin_amdgcn_mfma_f32_16x16x32_bf16(af[mt], bw[nt], acc[mt][nt], 0,0,0);
        #pragma unroll
        for (int nt = 0; nt < 2; ++nt) bw[nt] = bn[nt];
    }

    #pragma unroll
    for (int mt = 0; mt < 2; ++mt) {
        #pragma unroll
        for (int nt = 0; nt < 2; ++nt) {
            int n = nh*128 + w*32 + nt*16 + lm;
            float bb = Bi[n];
            #pragma unroll
            for (int j = 0; j < 4; ++j) {
                int m = m0 + mt*16 + lq*4 + j;
                U[(size_t)m*256 + n] = f2bf((acc[mt][nt][j] + bb) * sc);
            }
        }
    }
}

// ---------------------------------------------------------------- attn + conv, interleaved
// conv = round-14 form: 2 rows x 2 m-tiles, uniform LDS bases (measured-best).
__global__ __launch_bounds__(256) void attn_conv(
    const ushort* __restrict__ qab, const ushort* __restrict__ kab,
    const ushort* __restrict__ vab, const int* __restrict__ Rix,
    float* __restrict__ pl, ushort* __restrict__ pacc,
    const ushort* __restrict__ kvc,
    const ushort* __restrict__ wct, ushort* __restrict__ pconv)
{
    __shared__ __align__(16) ushort SMEM[19008];
    int tid = threadIdx.x;
    int grp = blockIdx.x / 9, rem = blockIdx.x - grp*9;
    if (rem < 5) {
        // ------------------------- conv block (cid = 0..639)
        int cid = grp*5 + rem;
        int ch = cid & 1;
        int t2 = cid >> 1;
        int rp = t2 / 5, dy = t2 - rp*5;
        int b = rp >> 5, y0 = (rp & 31)*2;

        const bf16x8 zero8 = (bf16x8){0,0,0,0,0,0,0,0};
        #pragma unroll
        for (int i = 0; i < 7; ++i) {
            int c = i*256 + tid;
            int row = (c >= 896);
            int cc = c - row*896;
            int pos = cc >> 5, off = (cc & 31)*8;
            int y = y0 + row + dy - 2;
            bf16x8 v = zero8;
            if (y >= 0 && y < 64 && pos >= 2 && pos < 26) {
                size_t sb = ((size_t)((b*64 + y)*24 + (pos - 2)))*256 + off;
                v = *(const bf16x8*)(kvc + sb);
            }
            *(bf16x8*)(&SMEM[row*9504 + pos*264 + off]) = v;
        }
        __syncthreads();

        int w = tid >> 6;
        int lane = tid & 63, lm = lane & 15, lq = lane >> 4;
        const ushort* bbase = wct + ((size_t)((dy*5)*256 + ch*128 + w*32 + lm))*256 + lq*8;
        const ushort* a00 = &SMEM[lm*264 + lq*8];

        f32x4 acc[2][2][2];
        #pragma unroll
        for (int r = 0; r < 2; ++r)
            #pragma unroll
            for (int mt = 0; mt < 2; ++mt)
                #pragma unroll
                for (int nt = 0; nt < 2; ++nt)
                    acc[r][mt][nt] = (f32x4){0.f,0.f,0.f,0.f};

        bf16x8 b0[2], b1[2];
        #pragma unroll
        for (int nt = 0; nt < 2; ++nt) b0[nt] = *(const bf16x8*)(bbase + nt*4096);
        #pragma unroll
        for (int nt = 0; nt < 2; ++nt) b1[nt] = *(const bf16x8*)(bbase + 32 + nt*4096);

        for (int iter = 0; iter < 40; ++iter) {
            int i2 = (iter + 2 < 40) ? iter + 2 : 39;
            int boff = (i2 >> 3)*65536 + (i2 & 7)*32;
            bf16x8 bn[2];
            #pragma unroll
            for (int nt = 0; nt < 2; ++nt) bn[nt] = *(const bf16x8*)(bbase + boff + nt*4096);

            int aoff = (iter >> 3)*264 + (iter & 7)*32;
            bf16x8 af[2][2];
            #pragma unroll
            for (int r = 0; r < 2; ++r)
                #pragma unroll
                for (int mt = 0; mt < 2; ++mt)
                    af[r][mt] = *(const bf16x8*)(a00 + r*9504 + mt*4224 + aoff);

            #pragma unroll
            for (int r = 0; r < 2; ++r)
                #pragma unroll
                for (int mt = 0; mt < 2; ++mt)
                    #pragma unroll
                    for (int nt = 0; nt < 2; ++nt)
                        acc[r][mt][nt] = __builtin_amdgcn_mfma_f32_16x16x32_bf16(
                            af[r][mt], b0[nt], acc[r][mt][nt], 0, 0, 0);

            #pragma unroll
            for (int nt = 0; nt < 2; ++nt) { b0[nt] = b1[nt]; b1[nt] = bn[nt]; }
        }

        #pragma unroll
        for (int r = 0; r < 2; ++r) {
            int grow = rp*2 + r;
            #pragma unroll
            for (int mt = 0; mt < 2; ++mt) {
                #pragma unroll
                for (int nt = 0; nt < 2; ++nt) {
                    int cob = ch*128 + w*32 + nt*16 + lm;
                    #pragma unroll
                    for (int j = 0; j < 4; ++j) {
                        int x = mt*16 + lq*4 + j;
                        if (x < 24)
                            pconv[((size_t)(dy*3072 + grow*24 + x))*256 + cob]
                                = f2bf(acc[r][mt][nt][j]);
                    }
                }
            }
        }
    } else {
        // ------------------------- attention block (aid = 0..511)
        int aid = grp*4 + (rem - 5);
        int bph = aid >> 2, kvb = aid & 3;
        int w = tid >> 6, lane = tid & 63;
        int lm = lane & 15, lq = lane >> 4;
        int bp = bph >> 3, h = bph & 7, b = bp >> 3;
        int r = Rix[bp*4 + kvb];
        int vrow0 = (b*8 + r)*192;
        ushort* P  = SMEM;
        ushort* Vs = SMEM + 2560;

        #pragma unroll
        for (int i = 0; i < 6; ++i) {
            int idx = i*256 + tid;
            int pos = idx >> 3, c4 = (idx & 7)*4;
            ushort4 v = *(const ushort4*)(vab + ((size_t)(vrow0 + pos))*256 + h*32 + c4);
            Vs[(c4+0)*200 + pos] = v.x;
            Vs[(c4+1)*200 + pos] = v.y;
            Vs[(c4+2)*200 + pos] = v.z;
            Vs[(c4+3)*200 + pos] = v.w;
        }

        bf16x8 qf[3];
        #pragma unroll
        for (int t = 0; t < 3; ++t)
            qf[t] = *(const bf16x8*)(qab + ((size_t)(bp*192 + w*48 + t*16 + lm))*256 + h*32 + lq*8);

        const ushort* kbase = kab + ((size_t)(vrow0))*256 + h*32 + lq*8;
        ushort* pw = P + w*640;
        __syncthreads();

        f32x4 O[3][2];
        #pragma unroll
        for (int t = 0; t < 3; ++t) { O[t][0] = (f32x4){0,0,0,0}; O[t][1] = (f32x4){0,0,0,0}; }
        float l[3] = {0.f, 0.f, 0.f};

        for (int k0 = 0; k0 < 192; k0 += 32) {
            bf16x8 kf0 = *(const bf16x8*)(kbase + (size_t)(k0 + lm)*256);
            bf16x8 kf1 = *(const bf16x8*)(kbase + (size_t)(k0 + 16 + lm)*256);
            bf16x8 vf0 = *(const bf16x8*)(&Vs[lm*200 + k0 + lq*8]);
            bf16x8 vf1 = *(const bf16x8*)(&Vs[(16 + lm)*200 + k0 + lq*8]);
            #pragma unroll
            for (int t = 0; t < 3; ++t) {
                f32x4 s0 = __builtin_amdgcn_mfma_f32_16x16x32_bf16(kf0, qf[t], (f32x4){0,0,0,0}, 0,0,0);
                f32x4 s1 = __builtin_amdgcn_mfma_f32_16x16x32_bf16(kf1, qf[t], (f32x4){0,0,0,0}, 0,0,0);
                float p0[4], p1[4];
                #pragma unroll
                for (int j = 0; j < 4; ++j) { p0[j] = __expf(s0[j]); p1[j] = __expf(s1[j]); }
                l[t] += p0[0]+p0[1]+p0[2]+p0[3] + p1[0]+p1[1]+p1[2]+p1[3];
                ushort4 a, c;
                a.x = f2bf(p0[0]); a.y = f2bf(p0[1]); a.z = f2bf(p0[2]); a.w = f2bf(p0[3]);
                c.x = f2bf(p1[0]); c.y = f2bf(p1[1]); c.z = f2bf(p1[2]); c.w = f2bf(p1[3]);
                *(ushort4*)(pw + lm*40 + lq*4)      = a;
                *(ushort4*)(pw + lm*40 + 16 + lq*4) = c;
                bf16x8 pf = *(const bf16x8*)(pw + lm*40 + lq*8);
                O[t][0] = __builtin_amdgcn_mfma_f32_16x16x32_bf16(pf, vf0, O[t][0], 0,0,0);
                O[t][1] = __builtin_amdgcn_mfma_f32_16x16x32_bf16(pf, vf1, O[t][1], 0,0,0);
            }
        }

        #pragma unroll
        for (int t = 0; t < 3; ++t) {
            float lt = l[t];
            lt += __shfl_xor(lt, 16);
            lt += __shfl_xor(lt, 32);
            size_t pbase = ((size_t)(bph*4 + kvb))*192 + w*48 + t*16;
            if (lq == 0) pl[pbase + lm] = lt;
            #pragma unroll
            for (int nt = 0; nt < 2; ++nt)
                #pragma unroll
                for (int reg = 0; reg < 4; ++reg)
                    pacc[(pbase + lq*4 + reg)*32 + nt*16 + lm] = f2bf(O[t][nt][reg]);
        }
    }
}

// ---------------------------------------------------------------- wo + merge + LN1 + reduce + LN2
// 16-row tiles, 192 blocks (kept from round 15 — measured win).
__global__ __launch_bounds__(256) void gemm_wo_ln2(
    const float* __restrict__ pl, const ushort* __restrict__ pacc,
    const ushort* __restrict__ T, const float* __restrict__ boa,
    const float* __restrict__ x,
    const float* __restrict__ g1, const float* __restrict__ b1,
    const ushort* __restrict__ pc, const float* __restrict__ cb,
    const float* __restrict__ g2, const float* __restrict__ b2,
    float* __restrict__ out)
{
    __shared__ __align__(16) ushort As[16*264];
    __shared__ float L2x[16*256];
    int tid = threadIdx.x;
    int m0 = blockIdx.x*16;
    #pragma unroll
    for (int i = 0; i < 2; ++i) {
        int c = i*256 + tid;
        int pos = c >> 5, off = (c & 31)*8;
        int m = m0 + pos;
        int bp = m / 192, q = m - bp*192;
        int h = off >> 5, d0 = off & 31;
        int bph = bp*8 + h;
        float ls = 0.f;
        float cv[8] = {0,0,0,0,0,0,0,0};
        #pragma unroll
        for (int k = 0; k < 4; ++k) {
            size_t pidx = ((size_t)(bph*4 + k))*192 + q;
            ls += pl[pidx];
            bf16x8 pv = *(const bf16x8*)(pacc + pidx*32 + d0);
            #pragma unroll
            for (int j = 0; j < 8; ++j) cv[j] += bf2f((ushort)pv[j]);
        }
        ushort o[8];
        #pragma unroll
        for (int j = 0; j < 8; ++j) o[j] = f2bf(cv[j] / ls);
        *(ushort4*)&As[pos*264 + off]     = make_ushort4(o[0],o[1],o[2],o[3]);
        *(ushort4*)&As[pos*264 + off + 4] = make_ushort4(o[4],o[5],o[6],o[7]);
    }
    __syncthreads();
    int w = tid >> 6, lane = tid & 63, lm = lane & 15, lq = lane >> 4;
    const ushort* tb = T + ((size_t)(w*64 + lm))*256 + lq*8;

    f32x4 acc[4];
    #pragma unroll
    for (int nt = 0; nt < 4; ++nt) acc[nt] = (f32x4){0.f,0.f,0.f,0.f};

    bf16x8 bw[4];
    #pragma unroll
    for (int nt = 0; nt < 4; ++nt) bw[nt] = *(const bf16x8*)(tb + nt*4096);

    for (int kc = 0; kc < 8; ++kc) {
        int nk = (kc + 1 < 8) ? kc + 1 : 7;
        bf16x8 bn[4];
        #pragma unroll
        for (int nt = 0; nt < 4; ++nt) bn[nt] = *(const bf16x8*)(tb + nt*4096 + nk*32);
        bf16x8 af = *(const bf16x8*)&As[lm*264 + kc*32 + lq*8];
        #pragma unroll
        for (int nt = 0; nt < 4; ++nt)
            acc[nt] = __builtin_amdgcn_mfma_f32_16x16x32_bf16(af, bw[nt], acc[nt], 0,0,0);
        #pragma unroll
        for (int nt = 0; nt < 4; ++nt) bw[nt] = bn[nt];
    }

    #pragma unroll
    for (int nt = 0; nt < 4; ++nt) {
        int n = w*64 + nt*16 + lm;
        float bb = boa[n];
        #pragma unroll
        for (int j = 0; j < 4; ++j) {
            int pos = lq*4 + j;
            float val = acc[nt][j] + bb;
            L2x[pos*256 + n] = val + x[(size_t)(m0 + pos)*256 + n];
        }
    }
    __syncthreads();
    #pragma unroll
    for (int rr = 0; rr < 4; ++rr) {
        int pos = w*4 + rr;
        int grow = m0 + pos;
        float4 a = *(const float4*)(&L2x[pos*256 + lane*4]);
        float x0 = a.x, x1 = a.y, x2 = a.z, x3 = a.w;
        float s  = x0 + x1 + x2 + x3;
        float sq = x0*x0 + x1*x1 + x2*x2 + x3*x3;
        #pragma unroll
        for (int off = 32; off > 0; off >>= 1) {
            s  += __shfl_xor(s,  off);
            sq += __shfl_xor(sq, off);
        }
        float mean = s * (1.0f/256.0f);
        float var  = sq * (1.0f/256.0f) - mean*mean;
        float rstd = rsqrtf(var + 1e-5f);
        float4 gv = *(const float4*)(g1 + lane*4);
        float4 bv = *(const float4*)(b1 + lane*4);
        float r0 = (x0 - mean)*rstd*gv.x + bv.x;
        float r1 = (x1 - mean)*rstd*gv.y + bv.y;
        float r2 = (x2 - mean)*rstd*gv.z + bv.z;
        float r3 = (x3 - mean)*rstd*gv.w + bv.w;
        size_t base = (size_t)grow*256 + lane*4;
        float4 gsum = *(const float4*)(cb + lane*4);
        #pragma unroll
        for (int d = 0; d < 5; ++d) {
            ushort4 v = *(const ushort4*)(pc + (size_t)d*NE + base);
            gsum.x += bf2f(v.x); gsum.y += bf2f(v.y);
            gsum.z += bf2f(v.z); gsum.w += bf2f(v.w);
        }
        float y0 = r0 + gsum.x, y1 = r1 + gsum.y, y2 = r2 + gsum.z, y3 = r3 + gsum.w;
        float s2v  = y0 + y1 + y2 + y3;
        float sq2  = y0*y0 + y1*y1 + y2*y2 + y3*y3;
        #pragma unroll
        for (int off = 32; off > 0; off >>= 1) {
            s2v += __shfl_xor(s2v, off);
            sq2 += __shfl_xor(sq2, off);
        }
        float mean2 = s2v * (1.0f/256.0f);
        float var2  = sq2 * (1.0f/256.0f) - mean2*mean2;
        float rstd2 = rsqrtf(var2 + 1e-5f);
        float4 g2v = *(const float4*)(g2 + lane*4);
        float4 b2v = *(const float4*)(b2 + lane*4);
        float4 o;
        o.x = (y0 - mean2)*rstd2*g2v.x + b2v.x;
        o.y = (y1 - mean2)*rstd2*g2v.y + b2v.y;
        o.z = (y2 - mean2)*rstd2*g2v.z + b2v.z;
        o.w = (y3 - mean2)*rstd2*g2v.w + b2v.w;
        *(float4*)(out + base) = o;
    }
}

// ---------------------------------------------------------------- launcher
extern "C" void kernel_launch(void* const* d_in, const int* in_sizes, int n_in,
                              void* d_out, int out_size, void* d_ws, size_t ws_size,
                              hipStream_t stream)
{
    (void)in_sizes; (void)n_in; (void)out_size; (void)ws_size;
    const float* x    = (const float*)d_in[0];
    const float* wq   = (const float*)d_in[1];
    const float* bq   = (const float*)d_in[2];
    const float* wk   = (const float*)d_in[3];
    const float* bk   = (const float*)d_in[4];
    const float* wv   = (const float*)d_in[5];
    const float* bv   = (const float*)d_in[6];
    const float* wqa  = (const float*)d_in[7];
    const float* bqa  = (const float*)d_in[8];
    const float* wka  = (const float*)d_in[9];
    const float* bka  = (const float*)d_in[10];
    const float* wva  = (const float*)d_in[11];
    const float* bva  = (const float*)d_in[12];
    const float* woa  = (const float*)d_in[13];
    const float* boa  = (const float*)d_in[14];
    const float* cw   = (const float*)d_in[15];
    const float* cbi  = (const float*)d_in[16];
    const float* ln1g = (const float*)d_in[17];
    const float* ln1b = (const float*)d_in[18];
    const float* ln2g = (const float*)d_in[19];
    const float* ln2b = (const float*)d_in[20];
    float* out = (float*)d_out;

    float* ws = (float*)d_ws;
    const size_t HNE = NE/2;
    ushort* qab = (ushort*)(ws + 0*HNE);
    ushort* kab = (ushort*)(ws + 1*HNE);
    ushort* vab = (ushort*)(ws + 2*HNE);
    ushort* kvc = (ushort*)(ws + 3*HNE);
    float* R    = ws + 4*HNE;
    ushort* pacc = (ushort*)R;
    float*  pl   = R + 1572864;
    ushort* pconv= (ushort*)(R + 1671168);
    ushort* wt7  = (ushort*)(R + 3637248);
    ushort* wstr = wt7 + 458752;
    ushort* wtc  = wstr + 196608;
    ushort* wtkv = wtc + 196608;
    ushort* wct  = wtkv + 65536;
    float* bcomp = (float*)(wct + 1638400);
    float* qloc  = bcomp + 1024;
    float* kloc  = qloc + 4096;
    int*   Rix   = (int*)(kloc + 4096);

    // 1. transposes + straight copies + routing descriptors
    wtransA<<<556, 256, 0, stream>>>(wq,wk,wv,wqa,wka,wva,woa, cw, wt7, wct, wstr,
                                     x, bq, bk, qloc, kloc);
    // 2. weight composition + topk (fused)
    compose<<<dim3(16,5), 256, 0, stream>>>(wt7, wstr, bq,bk,bv, bqa,bka,bva,
                                            wtc, wtkv, bcomp, qloc, kloc, Rix);
    // 3. quad GEMM: x -> qab, kab, vab, kvc
    gemm_quad<<<dim3(192,4), 256, 0, stream>>>(x, wtc, wtkv, bcomp, qab, kab, vab, kvc);
    // 4. attention + conv, interleaved; conv = round-14 2-m-tile form
    attn_conv<<<1152, 256, 0, stream>>>(qab, kab, vab, Rix, pl, pacc, kvc, wct, pconv);
    // 5. wo + merge + LN1 + conv-reduce + LN2 -> out (16-row tiles)
    gemm_wo_ln2<<<192, 256, 0, stream>>>(pl, pacc, wt7 + 393216, boa, x, ln1g, ln1b,
                                         pconv, cbi, ln2g, ln2b, out);
}

// Round 17
// 181.184 us; speedup vs baseline: 1.0354x; 1.0354x over previous
//
#include <hip/hip_runtime.h>
#include <hip/hip_bf16.h>

// DRSA temporal block. B=2, P=8, hp=8, W=24, C=256, NH=8, dk=32, kv=4, H=64.
// 4 dispatches: prep (all weight transposes + DIRECT-from-fp32 weight composition
// + qkloc; wt7/wstr intermediates eliminated, bit-identical rounding chains),
// gemm_quad(+topk plane), attn_conv (interleaved, round-14 conv form),
// gemm_wo_ln2 (16-row tiles).

#define NPOS 3072
#define CD   256
#define NE   (NPOS*CD)

typedef short bf16x8 __attribute__((ext_vector_type(8)));
typedef float f32x4  __attribute__((ext_vector_type(4)));

__device__ inline ushort f2bf(float f) {
    __hip_bfloat16 h = __float2bfloat16(f);   // RNE
    return *reinterpret_cast<ushort*>(&h);
}
__device__ inline float bf2f(ushort u) {
    unsigned v = ((unsigned)u) << 16;
    return *reinterpret_cast<float*>(&v);
}

// ---------------------------------------------------------------- prep: everything weight-side
// blk   0..399: conv tap transposes cw -> wct[tap][co][ci]
// blk 400..415: wo transpose w6 -> wwo[n][k]
// blk 416..447: qkloc (fp32-exact routing descriptors)
// blk 448..451: bcomp biases (identical rounding: bf2f(f2bf(Wxa)) weights)
// blk 452..499: wtc = (Wx·Wxa)^T DIRECT from fp32 (A transposed+converted in-block,
//               B converted inline; same f2bf per element as old wt7/wstr path)
// blk 500..515: wtkv = bf16(bf16(Wk)+bf16(Wv)) transposed, direct from fp32
__global__ __launch_bounds__(256) void prep(
    const float* __restrict__ w0, const float* __restrict__ w1, const float* __restrict__ w2,
    const float* __restrict__ w3, const float* __restrict__ w4, const float* __restrict__ w5,
    const float* __restrict__ w6, const float* __restrict__ cw,
    ushort* __restrict__ wct, ushort* __restrict__ wwo,
    ushort* __restrict__ wtc, ushort* __restrict__ wtkv,
    const float* __restrict__ x,
    const float* __restrict__ bq, const float* __restrict__ bk, const float* __restrict__ bv,
    const float* __restrict__ bqa, const float* __restrict__ bka, const float* __restrict__ bva,
    float* __restrict__ bcomp, float* __restrict__ qloc, float* __restrict__ kloc)
{
    __shared__ __align__(16) char SM[33280];
    int blk = blockIdx.x;
    int tid = threadIdx.x;
    if (blk < 416) {
        // -------- 64x64-tile transpose fp32 -> bf16 [n][k]
        float* l = (float*)SM;           // 64*65 fp32
        const float* M;
        ushort* D;
        int r2;
        if (blk < 400) {
            int tap = blk >> 4; r2 = blk & 15;
            M = cw + (size_t)tap*65536;
            D = wct + (size_t)tap*65536;
        } else {
            r2 = blk - 400;
            M = w6;
            D = wwo;
        }
        int ci0 = (r2 >> 2)*64, co0 = (r2 & 3)*64;
        int a = tid >> 6, c = tid & 63;
        #pragma unroll 4
        for (int k = 0; k < 16; ++k) {
            int cil = k*4 + a;
            l[cil*65 + c] = M[(size_t)(ci0 + cil)*256 + co0 + c];
        }
        __syncthreads();
        #pragma unroll 4
        for (int k = 0; k < 16; ++k) {
            int col = k*4 + a;
            D[((size_t)(co0 + col))*256 + ci0 + c] = f2bf(l[c*65 + col]);
        }
    } else if (blk < 448) {
        // -------- qkloc (fp32 exact; mean commutes with projection)
        float* l = (float*)SM;
        int q2 = blk - 416;
        int bp = q2 & 15, which = q2 >> 4;
        int c = tid;
        float s = 0.f;
        for (int i = 0; i < 192; ++i)
            s += x[((size_t)(bp*192 + i))*256 + c];
        l[c] = s * (1.0f/192.0f);
        __syncthreads();
        const float* W  = which ? w1 : w0;
        const float* Bv = which ? bk : bq;
        float* dst      = which ? kloc : qloc;
        float acc = Bv[c];
        #pragma unroll 8
        for (int k = 0; k < 256; ++k)
            acc += l[k] * W[(size_t)k*256 + c];
        dst[bp*256 + c] = acc;
    } else if (blk < 452) {
        // -------- composed biases (bit-identical: weights as bf2f(f2bf(fp32)))
        int bx = blk - 448;
        if (bx < 3) {
            const float* bsrc = bx==0 ? bq : (bx==1 ? bk : bv);
            const float* basr = bx==0 ? bqa : (bx==1 ? bka : bva);
            const float* wa   = bx==0 ? w3 : (bx==1 ? w4 : w5);
            float s = basr[tid];
            for (int k = 0; k < 256; ++k)
                s += bsrc[k] * bf2f(f2bf(wa[(size_t)k*256 + tid]));
            bcomp[bx*256 + tid] = s;
        } else {
            bcomp[3*256 + tid] = bk[tid] + bv[tid];
        }
    } else if (blk < 500) {
        // -------- wtc-direct: U = (Wx @ Wxa)^T in bf16, straight from fp32
        int b2 = blk - 452;
        int mat = b2 >> 4, r2 = b2 & 15;
        const float* Wa = mat==0 ? w3 : (mat==1 ? w4 : w5);   // [k][n] fp32
        const float* Wx = mat==0 ? w0 : (mat==1 ? w1 : w2);   // [k][n] fp32
        ushort* U = wtc + (size_t)mat*65536;
        int m0 = (r2 >> 1)*32, nh = r2 & 1;
        ushort* As = (ushort*)SM;             // 32*264 bf16
        float*  l  = (float*)(SM + 16896);    // 64*33 fp32 staging
        // stage As[m][kk] = f2bf(Wa[kk][m0+m])  (same rounding as old wt7[3+mat])
        for (int c4 = 0; c4 < 4; ++c4) {
            int kk0 = c4*64;
            #pragma unroll
            for (int i = 0; i < 8; ++i) {
                int idx = i*256 + tid;        // 64 rows x 32 cols
                int r = idx >> 5, c = idx & 31;
                l[r*33 + c] = Wa[(size_t)(kk0 + r)*256 + m0 + c];
            }
            __syncthreads();
            #pragma unroll
            for (int i = 0; i < 8; ++i) {
                int idx = i*256 + tid;        // 32 cols x 64 rows
                int c = idx >> 6, r = idx & 63;
                As[c*264 + kk0 + r] = f2bf(l[r*33 + c]);
            }
            __syncthreads();
        }
        int w = tid >> 6, lane = tid & 63, lm = lane & 15, lq = lane >> 4;
        const float* tbf = Wx + ((size_t)(nh*128 + w*32 + lm))*256 + lq*8;
        f32x4 acc[2][2];
        #pragma unroll
        for (int mt = 0; mt < 2; ++mt)
            #pragma unroll
            for (int nt = 0; nt < 2; ++nt) acc[mt][nt] = (f32x4){0.f,0.f,0.f,0.f};
        for (int kc = 0; kc < 8; ++kc) {
            bf16x8 bw[2];
            #pragma unroll
            for (int nt = 0; nt < 2; ++nt) {
                const float* p = tbf + nt*4096 + kc*32;
                float4 v0 = *(const float4*)p;
                float4 v1 = *(const float4*)(p + 4);
                bf16x8 bb;
                bb[0] = (short)f2bf(v0.x); bb[1] = (short)f2bf(v0.y);
                bb[2] = (short)f2bf(v0.z); bb[3] = (short)f2bf(v0.w);
                bb[4] = (short)f2bf(v1.x); bb[5] = (short)f2bf(v1.y);
                bb[6] = (short)f2bf(v1.z); bb[7] = (short)f2bf(v1.w);
                bw[nt] = bb;
            }
            bf16x8 af[2];
            #pragma unroll
            for (int mt = 0; mt < 2; ++mt)
                af[mt] = *(const bf16x8*)&As[(mt*16 + lm)*264 + kc*32 + lq*8];
            #pragma unroll
            for (int mt = 0; mt < 2; ++mt)
                #pragma unroll
                for (int nt = 0; nt < 2; ++nt)
                    acc[mt][nt] = __builtin_amdgcn_mfma_f32_16x16x32_bf16(af[mt], bw[nt], acc[mt][nt], 0,0,0);
        }
        #pragma unroll
        for (int mt = 0; mt < 2; ++mt)
            #pragma unroll
            for (int nt = 0; nt < 2; ++nt) {
                int n = nh*128 + w*32 + nt*16 + lm;
                #pragma unroll
                for (int j = 0; j < 4; ++j) {
                    int m = m0 + mt*16 + lq*4 + j;
                    U[(size_t)m*256 + n] = f2bf(acc[mt][nt][j]);
                }
            }
    } else {
        // -------- wtkv-direct: transposed bf16(bf16(Wk)+bf16(Wv))
        int r2 = blk - 500;
        int ci0 = (r2 >> 2)*64, co0 = (r2 & 3)*64;
        float* lk = (float*)SM;            // 64*65
        float* lv = lk + 64*65;            // 64*65
        int a = tid >> 6, c = tid & 63;
        #pragma unroll 4
        for (int k = 0; k < 16; ++k) {
            int cil = k*4 + a;
            size_t idx = (size_t)(ci0 + cil)*256 + co0 + c;
            lk[cil*65 + c] = w1[idx];
            lv[cil*65 + c] = w2[idx];
        }
        __syncthreads();
        #pragma unroll 4
        for (int k = 0; k < 16; ++k) {
            int col = k*4 + a;
            ushort ka = f2bf(lk[c*65 + col]);
            ushort va = f2bf(lv[c*65 + col]);
            wtkv[((size_t)(co0 + col))*256 + ci0 + c] = f2bf(bf2f(ka) + bf2f(va));
        }
    }
}

// ---------------------------------------------------------------- quad GEMM from x + topk plane
__global__ __launch_bounds__(256) void gemm_quad(
    const float* __restrict__ A,
    const ushort* __restrict__ wtc, const ushort* __restrict__ wtkv,
    const float* __restrict__ bcomp,
    ushort* __restrict__ U0, ushort* __restrict__ U1,
    ushort* __restrict__ U2, ushort* __restrict__ U3,
    const float* __restrict__ qloc, const float* __restrict__ kloc, int* __restrict__ Rix)
{
    __shared__ __align__(16) ushort As[32*264];
    int y = blockIdx.y;
    int tid = threadIdx.x;
    if (y == 4) {
        // topk (fp32 exact); blocks 0..1 = batch
        if (blockIdx.x >= 2) return;
        float* S = (float*)As;
        int b = blockIdx.x, t = tid;
        if (t < 64) {
            int p = t >> 3, qq = t & 7;
            float s = 0.f;
            for (int c = 0; c < 256; ++c)
                s += qloc[(b*8+p)*256 + c] * kloc[(b*8+qq)*256 + c];
            S[t] = s;
        }
        __syncthreads();
        if (t < 8) {
            float vals[8];
            #pragma unroll
            for (int j = 0; j < 8; ++j) vals[j] = S[t*8 + j];
            for (int j = 0; j < 4; ++j) {
                int best = 0; float bv2 = vals[0];
                #pragma unroll
                for (int i = 1; i < 8; ++i) if (vals[i] > bv2) { bv2 = vals[i]; best = i; }
                Rix[(b*8 + t)*4 + j] = best;
                vals[best] = -1e30f;
            }
        }
        return;
    }
    const ushort* T = (y < 3) ? (wtc + (size_t)y*65536) : wtkv;
    const float* Bi = bcomp + y*256;
    ushort* U = y==0 ? U0 : (y==1 ? U1 : (y==2 ? U2 : U3));
    float sc = (y == 0) ? 0.17677669529663687f : 1.0f;
    int m0 = (blockIdx.x >> 1)*32;
    int nh = blockIdx.x & 1;
    #pragma unroll
    for (int i = 0; i < 4; ++i) {
        int c = i*256 + tid;
        int pos = c >> 5, off = (c & 31)*8;
        const float* src = A + (size_t)(m0 + pos)*256 + off;
        float4 v0 = *(const float4*)src;
        float4 v1 = *(const float4*)(src + 4);
        ushort4 o0, o1;
        o0.x = f2bf(v0.x); o0.y = f2bf(v0.y); o0.z = f2bf(v0.z); o0.w = f2bf(v0.w);
        o1.x = f2bf(v1.x); o1.y = f2bf(v1.y); o1.z = f2bf(v1.z); o1.w = f2bf(v1.w);
        *(ushort4*)&As[pos*264 + off]     = o0;
        *(ushort4*)&As[pos*264 + off + 4] = o1;
    }
    __syncthreads();
    int w = tid >> 6, lane = tid & 63, lm = lane & 15, lq = lane >> 4;
    const ushort* tb = T + ((size_t)(nh*128 + w*32 + lm))*256 + lq*8;

    f32x4 acc[2][2];
    #pragma unroll
    for (int mt = 0; mt < 2; ++mt)
        #pragma unroll
        for (int nt = 0; nt < 2; ++nt) acc[mt][nt] = (f32x4){0.f,0.f,0.f,0.f};

    bf16x8 bw[2];
    #pragma unroll
    for (int nt = 0; nt < 2; ++nt) bw[nt] = *(const bf16x8*)(tb + nt*4096);

    for (int kc = 0; kc < 8; ++kc) {
        int nk = (kc + 1 < 8) ? kc + 1 : 7;
        bf16x8 bn[2];
        #pragma unroll
        for (int nt = 0; nt < 2; ++nt) bn[nt] = *(const bf16x8*)(tb + nt*4096 + nk*32);
        bf16x8 af[2];
        #pragma unroll
        for (int mt = 0; mt < 2; ++mt)
            af[mt] = *(const bf16x8*)&As[(mt*16 + lm)*264 + kc*32 + lq*8];
        #pragma unroll
        for (int mt = 0; mt < 2; ++mt)
            #pragma unroll
            for (int nt = 0; nt < 2; ++nt)
                acc[mt][nt] = __builtin_amdgcn_mfma_f32_16x16x32_bf16(af[mt], bw[nt], acc[mt][nt], 0,0,0);
        #pragma unroll
        for (int nt = 0; nt < 2; ++nt) bw[nt] = bn[nt];
    }

    #pragma unroll
    for (int mt = 0; mt < 2; ++mt) {
        #pragma unroll
        for (int nt = 0; nt < 2; ++nt) {
            int n = nh*128 + w*32 + nt*16 + lm;
            float bb = Bi[n];
            #pragma unroll
            for (int j = 0; j < 4; ++j) {
                int m = m0 + mt*16 + lq*4 + j;
                U[(size_t)m*256 + n] = f2bf((acc[mt][nt][j] + bb) * sc);
            }
        }
    }
}

// ---------------------------------------------------------------- attn + conv, interleaved
// conv = round-14 form: 2 rows x 2 m-tiles, uniform LDS bases (measured-best ~48.6us).
__global__ __launch_bounds__(256) void attn_conv(
    const ushort* __restrict__ qab, const ushort* __restrict__ kab,
    const ushort* __restrict__ vab, const int* __restrict__ Rix,
    float* __restrict__ pl, ushort* __restrict__ pacc,
    const ushort* __restrict__ kvc,
    const ushort* __restrict__ wct, ushort* __restrict__ pconv)
{
    __shared__ __align__(16) ushort SMEM[19008];
    int tid = threadIdx.x;
    int grp = blockIdx.x / 9, rem = blockIdx.x - grp*9;
    if (rem < 5) {
        int cid = grp*5 + rem;
        int ch = cid & 1;
        int t2 = cid >> 1;
        int rp = t2 / 5, dy = t2 - rp*5;
        int b = rp >> 5, y0 = (rp & 31)*2;

        const bf16x8 zero8 = (bf16x8){0,0,0,0,0,0,0,0};
        #pragma unroll
        for (int i = 0; i < 7; ++i) {
            int c = i*256 + tid;
            int row = (c >= 896);
            int cc = c - row*896;
            int pos = cc >> 5, off = (cc & 31)*8;
            int y = y0 + row + dy - 2;
            bf16x8 v = zero8;
            if (y >= 0 && y < 64 && pos >= 2 && pos < 26) {
                size_t sb = ((size_t)((b*64 + y)*24 + (pos - 2)))*256 + off;
                v = *(const bf16x8*)(kvc + sb);
            }
            *(bf16x8*)(&SMEM[row*9504 + pos*264 + off]) = v;
        }
        __syncthreads();

        int w = tid >> 6;
        int lane = tid & 63, lm = lane & 15, lq = lane >> 4;
        const ushort* bbase = wct + ((size_t)((dy*5)*256 + ch*128 + w*32 + lm))*256 + lq*8;
        const ushort* a00 = &SMEM[lm*264 + lq*8];

        f32x4 acc[2][2][2];
        #pragma unroll
        for (int r = 0; r < 2; ++r)
            #pragma unroll
            for (int mt = 0; mt < 2; ++mt)
                #pragma unroll
                for (int nt = 0; nt < 2; ++nt)
                    acc[r][mt][nt] = (f32x4){0.f,0.f,0.f,0.f};

        bf16x8 b0[2], b1[2];
        #pragma unroll
        for (int nt = 0; nt < 2; ++nt) b0[nt] = *(const bf16x8*)(bbase + nt*4096);
        #pragma unroll
        for (int nt = 0; nt < 2; ++nt) b1[nt] = *(const bf16x8*)(bbase + 32 + nt*4096);

        for (int iter = 0; iter < 40; ++iter) {
            int i2 = (iter + 2 < 40) ? iter + 2 : 39;
            int boff = (i2 >> 3)*65536 + (i2 & 7)*32;
            bf16x8 bn[2];
            #pragma unroll
            for (int nt = 0; nt < 2; ++nt) bn[nt] = *(const bf16x8*)(bbase + boff + nt*4096);

            int aoff = (iter >> 3)*264 + (iter & 7)*32;
            bf16x8 af[2][2];
            #pragma unroll
            for (int r = 0; r < 2; ++r)
                #pragma unroll
                for (int mt = 0; mt < 2; ++mt)
                    af[r][mt] = *(const bf16x8*)(a00 + r*9504 + mt*4224 + aoff);

            #pragma unroll
            for (int r = 0; r < 2; ++r)
                #pragma unroll
                for (int mt = 0; mt < 2; ++mt)
                    #pragma unroll
                    for (int nt = 0; nt < 2; ++nt)
                        acc[r][mt][nt] = __builtin_amdgcn_mfma_f32_16x16x32_bf16(
                            af[r][mt], b0[nt], acc[r][mt][nt], 0, 0, 0);

            #pragma unroll
            for (int nt = 0; nt < 2; ++nt) { b0[nt] = b1[nt]; b1[nt] = bn[nt]; }
        }

        #pragma unroll
        for (int r = 0; r < 2; ++r) {
            int grow = rp*2 + r;
            #pragma unroll
            for (int mt = 0; mt < 2; ++mt) {
                #pragma unroll
                for (int nt = 0; nt < 2; ++nt) {
                    int cob = ch*128 + w*32 + nt*16 + lm;
                    #pragma unroll
                    for (int j = 0; j < 4; ++j) {
                        int x = mt*16 + lq*4 + j;
                        if (x < 24)
                            pconv[((size_t)(dy*3072 + grow*24 + x))*256 + cob]
                                = f2bf(acc[r][mt][nt][j]);
                    }
                }
            }
        }
    } else {
        int aid = grp*4 + (rem - 5);
        int bph = aid >> 2, kvb = aid & 3;
        int w = tid >> 6, lane = tid & 63;
        int lm = lane & 15, lq = lane >> 4;
        int bp = bph >> 3, h = bph & 7, b = bp >> 3;
        int r = Rix[bp*4 + kvb];
        int vrow0 = (b*8 + r)*192;
        ushort* P  = SMEM;
        ushort* Vs = SMEM + 2560;

        #pragma unroll
        for (int i = 0; i < 6; ++i) {
            int idx = i*256 + tid;
            int pos = idx >> 3, c4 = (idx & 7)*4;
            ushort4 v = *(const ushort4*)(vab + ((size_t)(vrow0 + pos))*256 + h*32 + c4);
            Vs[(c4+0)*200 + pos] = v.x;
            Vs[(c4+1)*200 + pos] = v.y;
            Vs[(c4+2)*200 + pos] = v.z;
            Vs[(c4+3)*200 + pos] = v.w;
        }

        bf16x8 qf[3];
        #pragma unroll
        for (int t = 0; t < 3; ++t)
            qf[t] = *(const bf16x8*)(qab + ((size_t)(bp*192 + w*48 + t*16 + lm))*256 + h*32 + lq*8);

        const ushort* kbase = kab + ((size_t)(vrow0))*256 + h*32 + lq*8;
        ushort* pw = P + w*640;
        __syncthreads();

        f32x4 O[3][2];
        #pragma unroll
        for (int t = 0; t < 3; ++t) { O[t][0] = (f32x4){0,0,0,0}; O[t][1] = (f32x4){0,0,0,0}; }
        float l[3] = {0.f, 0.f, 0.f};

        for (int k0 = 0; k0 < 192; k0 += 32) {
            bf16x8 kf0 = *(const bf16x8*)(kbase + (size_t)(k0 + lm)*256);
            bf16x8 kf1 = *(const bf16x8*)(kbase + (size_t)(k0 + 16 + lm)*256);
            bf16x8 vf0 = *(const bf16x8*)(&Vs[lm*200 + k0 + lq*8]);
            bf16x8 vf1 = *(const bf16x8*)(&Vs[(16 + lm)*200 + k0 + lq*8]);
            #pragma unroll
            for (int t = 0; t < 3; ++t) {
                f32x4 s0 = __builtin_amdgcn_mfma_f32_16x16x32_bf16(kf0, qf[t], (f32x4){0,0,0,0}, 0,0,0);
                f32x4 s1 = __builtin_amdgcn_mfma_f32_16x16x32_bf16(kf1, qf[t], (f32x4){0,0,0,0}, 0,0,0);
                float p0[4], p1[4];
                #pragma unroll
                for (int j = 0; j < 4; ++j) { p0[j] = __expf(s0[j]); p1[j] = __expf(s1[j]); }
                l[t] += p0[0]+p0[1]+p0[2]+p0[3] + p1[0]+p1[1]+p1[2]+p1[3];
                ushort4 a, c;
                a.x = f2bf(p0[0]); a.y = f2bf(p0[1]); a.z = f2bf(p0[2]); a.w = f2bf(p0[3]);
                c.x = f2bf(p1[0]); c.y = f2bf(p1[1]); c.z = f2bf(p1[2]); c.w = f2bf(p1[3]);
                *(ushort4*)(pw + lm*40 + lq*4)      = a;
                *(ushort4*)(pw + lm*40 + 16 + lq*4) = c;
                bf16x8 pf = *(const bf16x8*)(pw + lm*40 + lq*8);
                O[t][0] = __builtin_amdgcn_mfma_f32_16x16x32_bf16(pf, vf0, O[t][0], 0,0,0);
                O[t][1] = __builtin_amdgcn_mfma_f32_16x16x32_bf16(pf, vf1, O[t][1], 0,0,0);
            }
        }

        #pragma unroll
        for (int t = 0; t < 3; ++t) {
            float lt = l[t];
            lt += __shfl_xor(lt, 16);
            lt += __shfl_xor(lt, 32);
            size_t pbase = ((size_t)(bph*4 + kvb))*192 + w*48 + t*16;
            if (lq == 0) pl[pbase + lm] = lt;
            #pragma unroll
            for (int nt = 0; nt < 2; ++nt)
                #pragma unroll
                for (int reg = 0; reg < 4; ++reg)
                    pacc[(pbase + lq*4 + reg)*32 + nt*16 + lm] = f2bf(O[t][nt][reg]);
        }
    }
}

// ---------------------------------------------------------------- wo + merge + LN1 + reduce + LN2
__global__ __launch_bounds__(256) void gemm_wo_ln2(
    const float* __restrict__ pl, const ushort* __restrict__ pacc,
    const ushort* __restrict__ T, const float* __restrict__ boa,
    const float* __restrict__ x,
    const float* __restrict__ g1, const float* __restrict__ b1,
    const ushort* __restrict__ pc, const float* __restrict__ cb,
    const float* __restrict__ g2, const float* __restrict__ b2,
    float* __restrict__ out)
{
    __shared__ __align__(16) ushort As[16*264];
    __shared__ float L2x[16*256];
    int tid = threadIdx.x;
    int m0 = blockIdx.x*16;
    #pragma unroll
    for (int i = 0; i < 2; ++i) {
        int c = i*256 + tid;
        int pos = c >> 5, off = (c & 31)*8;
        int m = m0 + pos;
        int bp = m / 192, q = m - bp*192;
        int h = off >> 5, d0 = off & 31;
        int bph = bp*8 + h;
        float ls = 0.f;
        float cv[8] = {0,0,0,0,0,0,0,0};
        #pragma unroll
        for (int k = 0; k < 4; ++k) {
            size_t pidx = ((size_t)(bph*4 + k))*192 + q;
            ls += pl[pidx];
            bf16x8 pv = *(const bf16x8*)(pacc + pidx*32 + d0);
            #pragma unroll
            for (int j = 0; j < 8; ++j) cv[j] += bf2f((ushort)pv[j]);
        }
        ushort o[8];
        #pragma unroll
        for (int j = 0; j < 8; ++j) o[j] = f2bf(cv[j] / ls);
        *(ushort4*)&As[pos*264 + off]     = make_ushort4(o[0],o[1],o[2],o[3]);
        *(ushort4*)&As[pos*264 + off + 4] = make_ushort4(o[4],o[5],o[6],o[7]);
    }
    __syncthreads();
    int w = tid >> 6, lane = tid & 63, lm = lane & 15, lq = lane >> 4;
    const ushort* tb = T + ((size_t)(w*64 + lm))*256 + lq*8;

    f32x4 acc[4];
    #pragma unroll
    for (int nt = 0; nt < 4; ++nt) acc[nt] = (f32x4){0.f,0.f,0.f,0.f};

    bf16x8 bw[4];
    #pragma unroll
    for (int nt = 0; nt < 4; ++nt) bw[nt] = *(const bf16x8*)(tb + nt*4096);

    for (int kc = 0; kc < 8; ++kc) {
        int nk = (kc + 1 < 8) ? kc + 1 : 7;
        bf16x8 bn[4];
        #pragma unroll
        for (int nt = 0; nt < 4; ++nt) bn[nt] = *(const bf16x8*)(tb + nt*4096 + nk*32);
        bf16x8 af = *(const bf16x8*)&As[lm*264 + kc*32 + lq*8];
        #pragma unroll
        for (int nt = 0; nt < 4; ++nt)
            acc[nt] = __builtin_amdgcn_mfma_f32_16x16x32_bf16(af, bw[nt], acc[nt], 0,0,0);
        #pragma unroll
        for (int nt = 0; nt < 4; ++nt) bw[nt] = bn[nt];
    }

    #pragma unroll
    for (int nt = 0; nt < 4; ++nt) {
        int n = w*64 + nt*16 + lm;
        float bb = boa[n];
        #pragma unroll
        for (int j = 0; j < 4; ++j) {
            int pos = lq*4 + j;
            float val = acc[nt][j] + bb;
            L2x[pos*256 + n] = val + x[(size_t)(m0 + pos)*256 + n];
        }
    }
    __syncthreads();
    #pragma unroll
    for (int rr = 0; rr < 4; ++rr) {
        int pos = w*4 + rr;
        int grow = m0 + pos;
        float4 a = *(const float4*)(&L2x[pos*256 + lane*4]);
        float x0 = a.x, x1 = a.y, x2 = a.z, x3 = a.w;
        float s  = x0 + x1 + x2 + x3;
        float sq = x0*x0 + x1*x1 + x2*x2 + x3*x3;
        #pragma unroll
        for (int off = 32; off > 0; off >>= 1) {
            s  += __shfl_xor(s,  off);
            sq += __shfl_xor(sq, off);
        }
        float mean = s * (1.0f/256.0f);
        float var  = sq * (1.0f/256.0f) - mean*mean;
        float rstd = rsqrtf(var + 1e-5f);
        float4 gv = *(const float4*)(g1 + lane*4);
        float4 bv = *(const float4*)(b1 + lane*4);
        float r0 = (x0 - mean)*rstd*gv.x + bv.x;
        float r1 = (x1 - mean)*rstd*gv.y + bv.y;
        float r2 = (x2 - mean)*rstd*gv.z + bv.z;
        float r3 = (x3 - mean)*rstd*gv.w + bv.w;
        size_t base = (size_t)grow*256 + lane*4;
        float4 gsum = *(const float4*)(cb + lane*4);
        #pragma unroll
        for (int d = 0; d < 5; ++d) {
            ushort4 v = *(const ushort4*)(pc + (size_t)d*NE + base);
            gsum.x += bf2f(v.x); gsum.y += bf2f(v.y);
            gsum.z += bf2f(v.z); gsum.w += bf2f(v.w);
        }
        float y0 = r0 + gsum.x, y1 = r1 + gsum.y, y2 = r2 + gsum.z, y3 = r3 + gsum.w;
        float s2v  = y0 + y1 + y2 + y3;
        float sq2  = y0*y0 + y1*y1 + y2*y2 + y3*y3;
        #pragma unroll
        for (int off = 32; off > 0; off >>= 1) {
            s2v += __shfl_xor(s2v, off);
            sq2 += __shfl_xor(sq2, off);
        }
        float mean2 = s2v * (1.0f/256.0f);
        float var2  = sq2 * (1.0f/256.0f) - mean2*mean2;
        float rstd2 = rsqrtf(var2 + 1e-5f);
        float4 g2v = *(const float4*)(g2 + lane*4);
        float4 b2v = *(const float4*)(b2 + lane*4);
        float4 o;
        o.x = (y0 - mean2)*rstd2*g2v.x + b2v.x;
        o.y = (y1 - mean2)*rstd2*g2v.y + b2v.y;
        o.z = (y2 - mean2)*rstd2*g2v.z + b2v.z;
        o.w = (y3 - mean2)*rstd2*g2v.w + b2v.w;
        *(float4*)(out + base) = o;
    }
}

// ---------------------------------------------------------------- launcher
extern "C" void kernel_launch(void* const* d_in, const int* in_sizes, int n_in,
                              void* d_out, int out_size, void* d_ws, size_t ws_size,
                              hipStream_t stream)
{
    (void)in_sizes; (void)n_in; (void)out_size; (void)ws_size;
    const float* x    = (const float*)d_in[0];
    const float* wq   = (const float*)d_in[1];
    const float* bq   = (const float*)d_in[2];
    const float* wk   = (const float*)d_in[3];
    const float* bk   = (const float*)d_in[4];
    const float* wv   = (const float*)d_in[5];
    const float* bv   = (const float*)d_in[6];
    const float* wqa  = (const float*)d_in[7];
    const float* bqa  = (const float*)d_in[8];
    const float* wka  = (const float*)d_in[9];
    const float* bka  = (const float*)d_in[10];
    const float* wva  = (const float*)d_in[11];
    const float* bva  = (const float*)d_in[12];
    const float* woa  = (const float*)d_in[13];
    const float* boa  = (const float*)d_in[14];
    const float* cw   = (const float*)d_in[15];
    const float* cbi  = (const float*)d_in[16];
    const float* ln1g = (const float*)d_in[17];
    const float* ln1b = (const float*)d_in[18];
    const float* ln2g = (const float*)d_in[19];
    const float* ln2b = (const float*)d_in[20];
    float* out = (float*)d_out;

    float* ws = (float*)d_ws;
    const size_t HNE = NE/2;
    ushort* qab = (ushort*)(ws + 0*HNE);
    ushort* kab = (ushort*)(ws + 1*HNE);
    ushort* vab = (ushort*)(ws + 2*HNE);
    ushort* kvc = (ushort*)(ws + 3*HNE);
    float* R    = ws + 4*HNE;
    ushort* pacc = (ushort*)R;
    float*  pl   = R + 1572864;
    ushort* pconv= (ushort*)(R + 1671168);
    ushort* wwo  = (ushort*)(R + 3637248);           // 65536 bf16
    ushort* wtc  = wwo + 65536;                      // 3*65536
    ushort* wtkv = wtc + 196608;                     // 65536
    ushort* wct  = wtkv + 65536;                     // 25*65536
    float* bcomp = (float*)(wct + 1638400);
    float* qloc  = bcomp + 1024;
    float* kloc  = qloc + 4096;
    int*   Rix   = (int*)(kloc + 4096);

    // 1. prep: all weight-side work + routing descriptors (one dispatch)
    prep<<<516, 256, 0, stream>>>(wq,wk,wv,wqa,wka,wva,woa, cw,
                                  wct, wwo, wtc, wtkv,
                                  x, bq,bk,bv, bqa,bka,bva,
                                  bcomp, qloc, kloc);
    // 2. quad GEMM: x -> qab, kab, vab, kvc  (+topk plane y=4)
    gemm_quad<<<dim3(192,5), 256, 0, stream>>>(x, wtc, wtkv, bcomp,
                                               qab, kab, vab, kvc, qloc, kloc, Rix);
    // 3. attention + conv, interleaved
    attn_conv<<<1152, 256, 0, stream>>>(qab, kab, vab, Rix, pl, pacc, kvc, wct, pconv);
    // 4. wo + merge + LN1 + conv-reduce + LN2 -> out
    gemm_wo_ln2<<<192, 256, 0, stream>>>(pl, pacc, wwo, boa, x, ln1g, ln1b,
                                         pconv, cbi, ln2g, ln2b, out);
}